// Round 1
// baseline (80.335 us; speedup 1.0000x reference)
//
#include <hip/hip_runtime.h>
#include <hip/hip_bf16.h>

typedef __bf16 bf16x8 __attribute__((ext_vector_type(8)));
typedef float f32x4 __attribute__((ext_vector_type(4)));

#define NUM_TEAMS 100000
#define NUM_MATCHES 1000000
#define LOG2E 1.4426950408889634f
#define NWG 1563            // one block per 64-team tile (full 128 hcols)
#define XQ 195              // NWG/8
#define XR 3                // NWG%8

__device__ __forceinline__ unsigned short f2bf(float x) {
    __hip_bfloat16 h = __float2bfloat16(x);
    return reinterpret_cast<unsigned short&>(h);
}
// single-instruction packed f32x2 -> bf16x2. No builtin on gfx950 (m240) -> asm.
__device__ __forceinline__ unsigned int cvtpk(float a, float b) {
    unsigned int r;
    asm("v_cvt_pk_bf16_f32 %0, %1, %2" : "=v"(r) : "v"(a), "v"(b));
    return r;
}
__device__ __forceinline__ float exp2_(float x) {
    float r; asm("v_exp_f32 %0, %1" : "=v"(r) : "v"(x)); return r;
}
__device__ __forceinline__ float rcp_(float x) {
    float r; asm("v_rcp_f32 %0, %1" : "=v"(r) : "v"(x)); return r;
}
// async global->LDS, 16B per lane. Dest = wave-uniform base + lane*16 (m104/m108).
__device__ __forceinline__ void load_lds16(const float* g, float* l) {
    __builtin_amdgcn_global_load_lds(
        (const __attribute__((address_space(1))) void*)g,
        (__attribute__((address_space(3))) void*)l, 16, 0, 0);
}

// ---------------- prep: pack W fragment-major bf16; biases pre-scaled by log2e ----------------
// Wpk u16 index = G*16384 + gate*4096 + ks*512 + l4*128 + l15*8 + e
//   holds W[row = gate*128 + G*16 + l15][k = ks*32 + l4*8 + e]  (W = [W_ih | W_hh])
__global__ __launch_bounds__(256) void prep_kernel(
    const float* __restrict__ W_ih, const float* __restrict__ W_hh,
    const float* __restrict__ b_ih, const float* __restrict__ b_hh,
    unsigned short* __restrict__ Wpk, float* __restrict__ biasc)
{
    int gid = blockIdx.x * 256 + threadIdx.x;   // 131072 bf16 elements
    int e = gid & 7;
    int chunk = gid >> 3;                        // 16B chunk id
    int l15 = chunk & 15;
    int l4 = (chunk >> 4) & 3;
    int rest = chunk >> 6;
    int ks = rest & 7;
    int gate = (rest >> 3) & 3;
    int G = rest >> 5;
    int row = gate * 128 + G * 16 + l15;
    int k = ks * 32 + l4 * 8 + e;
    float v = (k < 128) ? W_ih[row * 128 + k] : W_hh[row * 128 + (k - 128)];
    Wpk[gid] = f2bf(v);
    if (gid < 512) {
        float b = b_ih[gid] + b_hh[gid];
        float scale = ((gid >> 7) == 2) ? (2.0f * LOG2E) : (-LOG2E);
        biasc[gid] = b * scale;
    }
}

// ---------------- LSTM + fused full proj ----------------
// Block: 512 thr = 8 waves, one full 64-team x 128-hcol tile. Wave w owns hcols
// w*16..w*16+15 x 4 gates (G = w). A staged f32 [64][256] via global_load_lds
// (fire-and-forget, zero payload VGPRs); source-address XOR-swizzle (unit ^= row&7)
// so the linear LDS write lands swizzled; reader XORs identically -> conflict-optimal
// ds_read_b128. bf16 conversion (cvtpk, RNE — bit-identical to prior staging) moved
// into the K-loop. LDS 64KB(A, reused as h f32[64][128]) + 3KB(W) -> 2 blocks/CU,
// 16 waves/CU (register cap is 128/wave anyway: 64 VGPR + 64 AGPR acc).
__global__ __launch_bounds__(512, 4) void lstm_kernel(
    const float* __restrict__ inputs, const float* __restrict__ hx,
    const float* __restrict__ cx, const unsigned short* __restrict__ Wpk,
    const float* __restrict__ biasc, const float* __restrict__ W_out,
    float* __restrict__ projP)
{
    __shared__ __align__(16) float Af[64 * 256];    // 64 KB f32 A tile; reused as h[64][128]
    __shared__ float Wlds[768];
    const int tid = threadIdx.x;

    // bijective chunked XCD swizzle
    const int orig = blockIdx.x;
    const int xcd = orig & 7, idx = orig >> 3;
    const int tile = (xcd < XR ? xcd * (XQ + 1) : XR * (XQ + 1) + (xcd - XR) * XQ) + idx;
    const int brow = tile * 64;

    const int lane = tid & 63;
    const int w = tid >> 6;                          // wave 0..7
    const int l15 = lane & 15, l4 = lane >> 4;
    const int hcol = w * 16 + l15;                   // global 0..127

    // ---- stage A = [inputs | hx] f32 via global_load_lds: wave w stages row p*8+w ----
    // LDS[row][u] holds A[row][u ^ (row&7)] (16B units); row&7 == w for this wave.
    {
        const int su = lane ^ w;                     // source unit (involution swizzle)
        const int col = su * 4;
        const float* base = (col < 128) ? inputs + col : hx + (col - 128);
        #pragma unroll
        for (int p = 0; p < 8; ++p) {
            int row = p * 8 + w;
            int team = brow + row; if (team >= NUM_TEAMS) team = NUM_TEAMS - 1;
            load_lds16(base + (size_t)team * 128, Af + row * 256 + lane * 4);
        }
        Wlds[tid] = W_out[tid];
        if (tid < 256) Wlds[512 + tid] = W_out[512 + tid];
    }

    // B fragment base: group G = w, contiguous 1KB per wave-load (L2-resident)
    const unsigned short* bpg = Wpk + (size_t)w * 16384 + lane * 8;
    const float bic = biasc[hcol];                   // -c*bi
    const float bfc = biasc[128 + hcol];             // -c*bf
    const float bgc = biasc[256 + hcol];             // +2c*bg
    const float boc = biasc[384 + hcol];             // -c*bo
    // A-frag read offsets: unit s = ks*8 + l4*2 (+1); low3(s) ^ (row&7) with row&7 = l15&7
    const int u0 = ((l4 * 2) ^ (l15 & 7)) << 4;
    const int u1 = ((l4 * 2 + 1) ^ (l15 & 7)) << 4;

    f32x4 acc[4][4] = {};                            // [m][gate], 64 AGPRs

    asm volatile("s_waitcnt vmcnt(0)" ::: "memory"); // drain global_load_lds
    __syncthreads();

    const char* Ab = reinterpret_cast<const char*>(Af);
    #pragma unroll
    for (int ks = 0; ks < 8; ++ks) {                 // K = 256 in steps of 32
        bf16x8 b0 = *(const bf16x8*)(bpg + ks * 512);
        bf16x8 b1 = *(const bf16x8*)(bpg + 4096 + ks * 512);
        bf16x8 b2 = *(const bf16x8*)(bpg + 8192 + ks * 512);
        bf16x8 b3 = *(const bf16x8*)(bpg + 12288 + ks * 512);
        #pragma unroll
        for (int m = 0; m < 4; ++m) {
            const char* pa = Ab + (m * 16 + l15) * 1024 + ks * 128;
            f32x4 a0 = *reinterpret_cast<const f32x4*>(pa + u0);
            f32x4 a1 = *reinterpret_cast<const f32x4*>(pa + u1);
            union { uint4 q; bf16x8 v; } cc;
            cc.q.x = cvtpk(a0[0], a0[1]);
            cc.q.y = cvtpk(a0[2], a0[3]);
            cc.q.z = cvtpk(a1[0], a1[1]);
            cc.q.w = cvtpk(a1[2], a1[3]);
            bf16x8 af = cc.v;
            acc[m][0] = __builtin_amdgcn_mfma_f32_16x16x32_bf16(af, b0, acc[m][0], 0, 0, 0);
            acc[m][1] = __builtin_amdgcn_mfma_f32_16x16x32_bf16(af, b1, acc[m][1], 0, 0, 0);
            acc[m][2] = __builtin_amdgcn_mfma_f32_16x16x32_bf16(af, b2, acc[m][2], 0, 0, 0);
            acc[m][3] = __builtin_amdgcn_mfma_f32_16x16x32_bf16(af, b3, acc[m][3], 0, 0, 0);
        }
    }

    // issue cx loads before the barrier (latency hides under barrier wait)
    float cxa[16];
    #pragma unroll
    for (int m = 0; m < 4; ++m)
        #pragma unroll
        for (int j = 0; j < 4; ++j) {
            int team = brow + m * 16 + l4 * 4 + j;
            if (team >= NUM_TEAMS) team = NUM_TEAMS - 1;
            cxa[m * 4 + j] = cx[(size_t)team * 128 + hcol];
        }

    __syncthreads();                                 // all A reads done; LDS becomes h

    // ---- activations streamed per-m; h -> swizzled f32 [64][128] over Af ----
    // C/D layout: col = l15 -> hcol, row = l4*4 + j -> team-local
    {
        char* lb = reinterpret_cast<char*>(Af);
        #pragma unroll
        for (int m = 0; m < 4; ++m) {
            #pragma unroll
            for (int j = 0; j < 4; ++j) {
                float si = rcp_(1.0f + exp2_(fmaf(acc[m][0][j], -LOG2E, bic)));
                float sf = rcp_(1.0f + exp2_(fmaf(acc[m][1][j], -LOG2E, bfc)));
                float tg = fmaf(-2.0f, rcp_(1.0f + exp2_(fmaf(acc[m][2][j], 2.0f * LOG2E, bgc))), 1.0f);
                float so = rcp_(1.0f + exp2_(fmaf(acc[m][3][j], -LOG2E, boc)));
                float cn = fmaf(sf, cxa[m * 4 + j], si * tg);
                float tc = fmaf(-2.0f, rcp_(1.0f + exp2_(cn * (2.0f * LOG2E))), 1.0f);
                float hn = so * tc;
                int t = m * 16 + l4 * 4 + j;
                *reinterpret_cast<float*>(lb + ((t * 512 + hcol * 4) ^ ((t & 7) << 4))) = hn;
            }
        }
    }
    __syncthreads();

    // ---- fused full proj: 8 threads/team, 16 hcols each, 6 final outputs ----
    {
        int tl = tid >> 3, sub = tid & 7;            // team-local 0..63, sub 0..7
        const char* lb = reinterpret_cast<const char*>(Af);
        int hbase = tl * 512 + sub * 64;
        int hswz = (tl & 7) << 4;
        float a0 = 0.f, a1 = 0.f, a2 = 0.f, a3 = 0.f, a4 = 0.f, a5 = 0.f;
        #pragma unroll
        for (int c = 0; c < 4; ++c) {
            f32x4 h4 = *reinterpret_cast<const f32x4*>(lb + ((hbase + c * 16) ^ hswz));
            #pragma unroll
            for (int i = 0; i < 4; ++i) {
                float h = h4[i];
                int col = sub * 16 + c * 4 + i;                 // global hcol 0..127
                a0 += h * Wlds[col];       a1 += h * Wlds[256 + col]; a2 += h * Wlds[512 + col];
                a3 += h * Wlds[128 + col]; a4 += h * Wlds[384 + col]; a5 += h * Wlds[640 + col];
            }
        }
        a0 += __shfl_xor(a0, 1); a1 += __shfl_xor(a1, 1); a2 += __shfl_xor(a2, 1);
        a3 += __shfl_xor(a3, 1); a4 += __shfl_xor(a4, 1); a5 += __shfl_xor(a5, 1);
        a0 += __shfl_xor(a0, 2); a1 += __shfl_xor(a1, 2); a2 += __shfl_xor(a2, 2);
        a3 += __shfl_xor(a3, 2); a4 += __shfl_xor(a4, 2); a5 += __shfl_xor(a5, 2);
        a0 += __shfl_xor(a0, 4); a1 += __shfl_xor(a1, 4); a2 += __shfl_xor(a2, 4);
        a3 += __shfl_xor(a3, 4); a4 += __shfl_xor(a4, 4); a5 += __shfl_xor(a5, 4);
        int team = brow + tl;
        if (sub == 0 && team < NUM_TEAMS) {
            float4* o = reinterpret_cast<float4*>(projP + (size_t)team * 8);
            o[0] = make_float4(a0, a1, a2, a2);      // home (full sum)
            o[1] = make_float4(a3, a4, a5, a5);      // away (full sum)
        }
    }
}

// ---------------- match head: gather finals; logits + b_out ; softmax ----------------
__global__ __launch_bounds__(256) void match_kernel(
    const int* __restrict__ matches, const float* __restrict__ projP,
    const float* __restrict__ b_out, float* __restrict__ out)
{
    int m = blockIdx.x * 256 + threadIdx.x;
    if (m >= NUM_MATCHES) return;
    int2 mi = reinterpret_cast<const int2*>(matches)[m];
    const float4* pp = reinterpret_cast<const float4*>(projP);
    float4 hv = pp[(size_t)mi.x * 2 + 0];            // home
    float4 av = pp[(size_t)mi.y * 2 + 1];            // away
    float l0 = hv.x + av.x + b_out[0];
    float l1 = hv.y + av.y + b_out[1];
    float l2 = hv.z + av.z + b_out[2];
    float mx = fmaxf(l0, fmaxf(l1, l2));
    float e0 = __expf(l0 - mx), e1 = __expf(l1 - mx), e2 = __expf(l2 - mx);
    float inv = 1.0f / (e0 + e1 + e2);
    out[3 * m + 0] = e0 * inv;
    out[3 * m + 1] = e1 * inv;
    out[3 * m + 2] = e2 * inv;
}

extern "C" void kernel_launch(void* const* d_in, const int* in_sizes, int n_in,
                              void* d_out, int out_size, void* d_ws, size_t ws_size,
                              hipStream_t stream) {
    const float* inputs = (const float*)d_in[0];
    const float* hx     = (const float*)d_in[1];
    const float* cx     = (const float*)d_in[2];
    const int*   matches= (const int*)d_in[3];
    const float* W_ih   = (const float*)d_in[4];
    const float* W_hh   = (const float*)d_in[5];
    const float* b_ih   = (const float*)d_in[6];
    const float* b_hh   = (const float*)d_in[7];
    const float* W_out  = (const float*)d_in[8];
    const float* b_out  = (const float*)d_in[9];
    float* out = (float*)d_out;

    char* ws = (char*)d_ws;
    unsigned short* Wpk  = (unsigned short*)ws;                  // 256 KB fragment-major
    float* biasc         = (float*)(ws + 262144);                // 2 KB
    float* projP         = (float*)(ws + (1 << 20));             // 100000*8*4 = 3.2 MB

    prep_kernel <<<512, 256, 0, stream>>>(W_ih, W_hh, b_ih, b_hh, Wpk, biasc);
    lstm_kernel <<<NWG, 512, 0, stream>>>(inputs, hx, cx, Wpk, biasc, W_out, projP);
    match_kernel<<<(NUM_MATCHES + 255) / 256, 256, 0, stream>>>(matches, projP, b_out, out);
}